// Round 3
// baseline (773.828 us; speedup 1.0000x reference)
//
#include <hip/hip_runtime.h>
#include <float.h>

// MaxPoolAggregator: out[q, :] = max over s of features[nbrs[q,s], :]
// features: float32 [N_NODES, 128]   (512 B per row)
// nbrs:     int32   [N_QUERY, S]
// out:      float32 [N_QUERY, 128]
//
// R3 (= R2 resubmit, ASCII-clean): the direct random gather runs at
// ~1.8 TB/s because random 512 B rows shatter DRAM page locality per HBM
// channel (sequential fills on this chip hit 6.4 TB/s). Restructure as P
// passes over 128 MB feature chunks: sequentially stream the chunk into
// Infinity Cache (memory-side L3 caches all HBM reads), then gather
// in-chunk neighbors (served from L3) and fmax-RMW into out. Max is
// associative with identity -FLT_MAX, so passwise accumulation is exact.

typedef __attribute__((ext_vector_type(4))) float f32x4;

// ---- Pass A: sequential streamer pulls a feature chunk through L3.
__global__ __launch_bounds__(256) void prefetch_chunk(
    const f32x4* __restrict__ p, long n16)
{
    long i = (long)blockIdx.x * blockDim.x + threadIdx.x;
    long stride = (long)gridDim.x * blockDim.x;
    float acc = 0.f;
    for (; i < n16; i += stride) {
        f32x4 v = p[i];
        acc += v[0] + v[1] + v[2] + v[3];
    }
    asm volatile("" :: "v"(acc));   // keep loads live (no DCE); no store
}

// ---- Pass B: gather neighbors with id in [lo, hi), fmax-RMW into out.
// 32 lanes per query, lane g owns float4 chunk g of the 512 B row.
template <int S>
__global__ __launch_bounds__(256, 8) void maxpool_pass(
    const float* __restrict__ feats,
    const int* __restrict__ nbrs,
    float* __restrict__ out,
    int n_query, int lo, int hi, int first)
{
    int idx = blockIdx.x * blockDim.x + threadIdx.x;
    int q = idx >> 5;
    int g = idx & 31;
    if (q >= n_query) return;

    // Cooperative index fetch: lanes 0..S-1 load one index each.
    int nbr_l = 0;
    if (g < S) nbr_l = nbrs[(long)q * S + g];

    const char* fb = (const char*)feats;
    const unsigned goff = (unsigned)g * 16u;

    f32x4 m = { -FLT_MAX, -FLT_MAX, -FLT_MAX, -FLT_MAX };
    bool any = false;
    #pragma unroll
    for (int s = 0; s < S; ++s) {
        int nbr = __shfl(nbr_l, s, 32);          // uniform within the 32-lane group
        if (nbr >= lo && nbr < hi) {
            unsigned off = (unsigned)nbr * 512u + goff;
            f32x4 v = *(const f32x4*)(fb + off); // expected L3 hit
            m[0] = fmaxf(m[0], v[0]);
            m[1] = fmaxf(m[1], v[1]);
            m[2] = fmaxf(m[2], v[2]);
            m[3] = fmaxf(m[3], v[3]);
            any = true;
        }
    }

    f32x4* op = (f32x4*)(out + (size_t)q * 128) + g;
    if (first) {
        // Initialize output (overwrites any poison). -FLT_MAX where the
        // query had no neighbor in this chunk; later passes RMW it up.
        *op = m;
    } else if (any) {
        f32x4 o = *op;
        o[0] = fmaxf(o[0], m[0]);
        o[1] = fmaxf(o[1], m[1]);
        o[2] = fmaxf(o[2], m[2]);
        o[3] = fmaxf(o[3], m[3]);
        *op = o;
    }
}

// ---- Direct single-pass kernel (features fit in L3).
template <int S>
__global__ __launch_bounds__(256, 8) void maxpool_direct(
    const float* __restrict__ feats,
    const int* __restrict__ nbrs,
    float* __restrict__ out,
    int n_query)
{
    int idx = blockIdx.x * blockDim.x + threadIdx.x;
    int q = idx >> 5;
    int g = idx & 31;
    if (q >= n_query) return;

    int nbr_l = 0;
    if (g < S) nbr_l = nbrs[(long)q * S + g];

    const char* fb = (const char*)feats;
    const unsigned goff = (unsigned)g * 16u;

    f32x4 m;
    {
        unsigned off = (unsigned)__shfl(nbr_l, 0, 32) * 512u + goff;
        m = *(const f32x4*)(fb + off);
    }
    #pragma unroll
    for (int s = 1; s < S; ++s) {
        unsigned off = (unsigned)__shfl(nbr_l, s, 32) * 512u + goff;
        f32x4 v = *(const f32x4*)(fb + off);
        m[0] = fmaxf(m[0], v[0]);
        m[1] = fmaxf(m[1], v[1]);
        m[2] = fmaxf(m[2], v[2]);
        m[3] = fmaxf(m[3], v[3]);
    }
    *((f32x4*)(out + (size_t)q * 128) + g) = m;
}

// ---- Generic fallback for num_sample != 10 (correctness path).
__global__ __launch_bounds__(256) void maxpool_generic(
    const float* __restrict__ feats,
    const int* __restrict__ nbrs,
    float* __restrict__ out,
    int n_query, int num_sample)
{
    int idx = blockIdx.x * blockDim.x + threadIdx.x;
    int q = idx >> 5;
    int g = idx & 31;
    if (q >= n_query) return;

    const long base = (long)q * num_sample;

    f32x4 m;
    {
        int nbr = nbrs[base];
        m = *((const f32x4*)(feats + (size_t)nbr * 128) + g);
    }
    for (int s = 1; s < num_sample; ++s) {
        int nbr = nbrs[base + s];
        f32x4 v = *((const f32x4*)(feats + (size_t)nbr * 128) + g);
        m[0] = fmaxf(m[0], v[0]);
        m[1] = fmaxf(m[1], v[1]);
        m[2] = fmaxf(m[2], v[2]);
        m[3] = fmaxf(m[3], v[3]);
    }
    *((f32x4*)(out + (size_t)q * 128) + g) = m;
}

extern "C" void kernel_launch(void* const* d_in, const int* in_sizes, int n_in,
                              void* d_out, int out_size, void* d_ws, size_t ws_size,
                              hipStream_t stream) {
    const float* feats = (const float*)d_in[0];
    const int*   nbrs  = (const int*)d_in[1];
    float*       out   = (float*)d_out;

    const int D = 128;
    int n_query    = out_size / D;
    int n_nodes    = in_sizes[0] / D;
    int num_sample = (n_query > 0) ? (in_sizes[1] / n_query) : 1;

    int total  = n_query * 32;               // 32 threads per query
    int blocks = (total + 255) / 256;

    if (num_sample != 10) {
        maxpool_generic<<<blocks, 256, 0, stream>>>(feats, nbrs, out, n_query, num_sample);
        return;
    }

    const long feat_bytes = (long)n_nodes * (long)D * (long)sizeof(float);
    if (feat_bytes <= (192L << 20)) {
        // Features (plus out) fit in Infinity Cache: direct gather.
        maxpool_direct<10><<<blocks, 256, 0, stream>>>(feats, nbrs, out, n_query);
        return;
    }

    // Tiled path: P chunks of the feature table, each staged through L3.
    const int P = 4;
    int chunk = (n_nodes + P - 1) / P;
    for (int p = 0; p < P; ++p) {
        int lo = p * chunk;
        int hi = lo + chunk; if (hi > n_nodes) hi = n_nodes;
        if (lo >= hi) break;
        long n16 = (long)(hi - lo) * (D / 4);          // f32x4 count in chunk
        prefetch_chunk<<<2048, 256, 0, stream>>>(
            (const f32x4*)(feats + (long)lo * D), n16);
        maxpool_pass<10><<<blocks, 256, 0, stream>>>(
            feats, nbrs, out, n_query, lo, hi, p == 0 ? 1 : 0);
    }
}